// Round 3
// baseline (173.302 us; speedup 1.0000x reference)
//
#include <hip/hip_runtime.h>
#include <hip/hip_bf16.h>

// LocalActivationUnit: score[b,t] = relu([q,k,q-k,q*k]·W0 + b0)·W1 + b1
// Folded form: Wb[e][h] = W0[128+e][h] - W0[256+e][h] + q[e]*W0[384+e][h]
//              bias[h]  = sum_e q[e]*(W0[e][h] + W0[256+e][h]) + b0[h]
//              h = relu(k·Wb + bias);  score = h·W1 + b1
// One block per batch b. Per-batch 200x128x64 bf16 MFMA GEMM, keys streamed
// from HBM exactly once (memory-bound target ~17us).

#define TB 200
#define EB 128
#define HB 64

typedef __attribute__((ext_vector_type(8))) short bf16x8;
typedef __attribute__((ext_vector_type(4))) float f32x4;

__global__ __launch_bounds__(256, 4)
void lau_kernel(const float* __restrict__ query,
                const float* __restrict__ keys,
                const float* __restrict__ W0,
                const float* __restrict__ b0,
                const float* __restrict__ W1,
                const float* __restrict__ b1,
                float* __restrict__ out)
{
    const int b   = blockIdx.x;
    const int tid = threadIdx.x;

    __shared__ float q_s[EB];
    __shared__ float bias_s[HB];
    __shared__ float w1_s[HB];
    __shared__ float red_s[256];
    // WbT[h][e] bf16, row stride 136 (136 % 32-banks phase = 4 -> only free
    // 2-way conflicts on ds_read_b128 across the 16 n-lanes)
    __shared__ __align__(16) __hip_bfloat16 wbt[HB][EB + 8];

    if (tid < EB) q_s[tid] = query[(size_t)b * EB + tid];
    __syncthreads();

    // ---- per-batch weight fold + bias partials ----
    {
        const int h     = tid & 63;
        const int chunk = tid >> 6;       // 0..3, each covers 32 e's
        float biasp = 0.f;
        #pragma unroll 8
        for (int i = 0; i < 32; ++i) {
            const int e = chunk * 32 + i;
            const float qe  = q_s[e];
            const float w0a = W0[(size_t)e            * HB + h];
            const float w0b = W0[(size_t)(EB + e)     * HB + h];
            const float w0c = W0[(size_t)(2 * EB + e) * HB + h];
            const float w0d = W0[(size_t)(3 * EB + e) * HB + h];
            wbt[h][e] = __float2bfloat16(w0b - w0c + qe * w0d);
            biasp += qe * (w0a + w0c);
        }
        red_s[tid] = biasp;
    }
    __syncthreads();
    if (tid < HB) {
        bias_s[tid] = red_s[tid] + red_s[tid + 64] + red_s[tid + 128] + red_s[tid + 192] + b0[tid];
        w1_s[tid]   = W1[tid];
    }
    __syncthreads();

    const int lane = tid & 63;
    const int wave = tid >> 6;
    const int ln15 = lane & 15;
    const int quad = lane >> 4;

    // ---- hoist all B fragments into registers (4 ntiles x 4 ksteps x 4 VGPR) ----
    // b-frag element j = Wb[k = ks*32 + quad*8 + j][n = nt*16 + ln15] = WbT[n][k..k+7]
    bf16x8 bfrag[4][4];
    #pragma unroll
    for (int nt = 0; nt < 4; ++nt) {
        #pragma unroll
        for (int ks = 0; ks < 4; ++ks) {
            bfrag[nt][ks] = *(const bf16x8*)&wbt[nt * 16 + ln15][ks * 32 + quad * 8];
        }
    }

    float w1q[4], biasq[4];
    #pragma unroll
    for (int nt = 0; nt < 4; ++nt) {
        w1q[nt]   = w1_s[nt * 16 + ln15];
        biasq[nt] = bias_s[nt * 16 + ln15];
    }

    const float* kb  = keys + (size_t)b * TB * EB;
    const float  b1v = b1[0];

    // 13 m-tiles of 16 rows cover T=200 (last tile half-masked)
    for (int mt = wave; mt < 13; mt += 4) {
        const int mrow = mt * 16 + ln15;           // A-operand row for this lane
        const int mc   = mrow < TB ? mrow : TB - 1; // clamp: valid mem, masked at store
        const float* arow = kb + (size_t)mc * EB + quad * 8;

        f32x4 acc[4] = {{0,0,0,0},{0,0,0,0},{0,0,0,0},{0,0,0,0}};
        #pragma unroll
        for (int ks = 0; ks < 4; ++ks) {
            const float4 a0 = *(const float4*)(arow + ks * 32);
            const float4 a1 = *(const float4*)(arow + ks * 32 + 4);
            union { bf16x8 v; __hip_bfloat162 h2[4]; } u;
            u.h2[0] = __float22bfloat162_rn(make_float2(a0.x, a0.y));
            u.h2[1] = __float22bfloat162_rn(make_float2(a0.z, a0.w));
            u.h2[2] = __float22bfloat162_rn(make_float2(a1.x, a1.y));
            u.h2[3] = __float22bfloat162_rn(make_float2(a1.z, a1.w));
            #pragma unroll
            for (int nt = 0; nt < 4; ++nt)
                acc[nt] = __builtin_amdgcn_mfma_f32_16x16x32_bf16(u.v, bfrag[nt][ks], acc[nt], 0, 0, 0);
        }

        // ---- epilogue: relu + bias, dot with W1, reduce over n (16 lanes) ----
        // C layout: n = ln15, m(in-tile) = quad*4 + r
        float part[4];
        #pragma unroll
        for (int r = 0; r < 4; ++r) {
            float s = 0.f;
            #pragma unroll
            for (int nt = 0; nt < 4; ++nt) {
                float hv = acc[nt][r] + biasq[nt];
                hv = hv > 0.f ? hv : 0.f;
                s += hv * w1q[nt];
            }
            part[r] = s;
        }
        #pragma unroll
        for (int m = 1; m < 16; m <<= 1) {
            #pragma unroll
            for (int r = 0; r < 4; ++r)
                part[r] += __shfl_xor(part[r], m, 64);
        }
        if (ln15 == 0) {
            #pragma unroll
            for (int r = 0; r < 4; ++r) {
                const int mg = mt * 16 + quad * 4 + r;
                if (mg < TB) out[(size_t)b * TB + mg] = part[r] + b1v;
            }
        }
    }
}

extern "C" void kernel_launch(void* const* d_in, const int* in_sizes, int n_in,
                              void* d_out, int out_size, void* d_ws, size_t ws_size,
                              hipStream_t stream) {
    const float* query = (const float*)d_in[0];
    const float* keys  = (const float*)d_in[1];
    const float* W0    = (const float*)d_in[2];
    const float* b0    = (const float*)d_in[3];
    const float* W1    = (const float*)d_in[4];
    const float* b1    = (const float*)d_in[5];
    float* out = (float*)d_out;

    lau_kernel<<<1024, 256, 0, stream>>>(query, keys, W0, b0, W1, b1, out);
}

// Round 4
// 170.256 us; speedup vs baseline: 1.0179x; 1.0179x over previous
//
#include <hip/hip_runtime.h>
#include <hip/hip_bf16.h>

// LocalActivationUnit: score[b,t] = relu([q,k,q-k,q*k]·W0 + b0)·W1 + b1
// Folded form: Wb[e][h] = W0[128+e][h] - W0[256+e][h] + q[e]*W0[384+e][h]
//              bias[h]  = sum_e q[e]*(W0[e][h] + W0[256+e][h]) + b0[h]
//              h = relu(k·Wb + bias);  score = h·W1 + b1
// One block per batch b. Per-batch 200x128x64 bf16 MFMA GEMM, keys streamed
// from HBM exactly once (memory-bound target ~17us).
//
// R3 -> R4: B-fragments are no longer hoisted into 64 VGPRs (that blew the
// 128-VGPR cap imposed by __launch_bounds__(256,4) and forced scratch spills,
// the suspected 10x). They are re-read from LDS each ks step instead; VGPR
// budget now ~100.

#define TB 200
#define EB 128
#define HB 64

typedef __attribute__((ext_vector_type(8))) short bf16x8;
typedef __attribute__((ext_vector_type(4))) float f32x4;

__global__ __launch_bounds__(256, 4)
void lau_kernel(const float* __restrict__ query,
                const float* __restrict__ keys,
                const float* __restrict__ W0,
                const float* __restrict__ b0,
                const float* __restrict__ W1,
                const float* __restrict__ b1,
                float* __restrict__ out)
{
    const int b   = blockIdx.x;
    const int tid = threadIdx.x;

    __shared__ float q_s[EB];
    __shared__ float bias_s[HB];
    __shared__ float w1_s[HB];
    __shared__ float red_s[256];
    // WbT[h][e] bf16, row stride 136 elems = 272 B. 272 % 128 == 16, so the
    // 16-byte ds_read_b128 fragments of lanes (ln15,quad) spread uniformly
    // across all 32 banks (structural minimum for b128).
    __shared__ __align__(16) __hip_bfloat16 wbt[HB][EB + 8];

    if (tid < EB) q_s[tid] = query[(size_t)b * EB + tid];
    __syncthreads();

    // ---- per-batch weight fold + bias partials ----
    {
        const int h     = tid & 63;
        const int chunk = tid >> 6;       // 0..3, each covers 32 e's
        float biasp = 0.f;
        #pragma unroll 8
        for (int i = 0; i < 32; ++i) {
            const int e = chunk * 32 + i;
            const float qe  = q_s[e];
            const float w0a = W0[(size_t)e            * HB + h];
            const float w0b = W0[(size_t)(EB + e)     * HB + h];
            const float w0c = W0[(size_t)(2 * EB + e) * HB + h];
            const float w0d = W0[(size_t)(3 * EB + e) * HB + h];
            wbt[h][e] = __float2bfloat16(w0b - w0c + qe * w0d);
            biasp += qe * (w0a + w0c);
        }
        red_s[tid] = biasp;
    }
    __syncthreads();
    if (tid < HB) {
        bias_s[tid] = red_s[tid] + red_s[tid + 64] + red_s[tid + 128] + red_s[tid + 192] + b0[tid];
        w1_s[tid]   = W1[tid];
    }
    __syncthreads();

    const int lane = tid & 63;
    const int wave = tid >> 6;
    const int ln15 = lane & 15;
    const int quad = lane >> 4;

    float w1q[4], biasq[4];
    #pragma unroll
    for (int nt = 0; nt < 4; ++nt) {
        w1q[nt]   = w1_s[nt * 16 + ln15];
        biasq[nt] = bias_s[nt * 16 + ln15];
    }

    // Per-lane LDS base for B-fragments: WbT[ln15][quad*8], nt adds 4352 B,
    // ks adds 64 B (32 elems) -> compiler folds into ds_read_b128 offsets.
    const __hip_bfloat16* wb_base = &wbt[ln15][quad * 8];

    const float* kb  = keys + (size_t)b * TB * EB;
    const float  b1v = b1[0];

    // 13 m-tiles of 16 rows cover T=200 (last tile half-masked)
    for (int mt = wave; mt < 13; mt += 4) {
        const int mrow = mt * 16 + ln15;           // A-operand row for this lane
        const int mc   = mrow < TB ? mrow : TB - 1; // clamp: valid mem, masked at store
        const float* arow = kb + (size_t)mc * EB + quad * 8;

        f32x4 acc[4] = {{0,0,0,0},{0,0,0,0},{0,0,0,0},{0,0,0,0}};
        #pragma unroll
        for (int ks = 0; ks < 4; ++ks) {
            const float4 a0 = *(const float4*)(arow + ks * 32);
            const float4 a1 = *(const float4*)(arow + ks * 32 + 4);
            union { bf16x8 v; __hip_bfloat162 h2[4]; } u;
            u.h2[0] = __float22bfloat162_rn(make_float2(a0.x, a0.y));
            u.h2[1] = __float22bfloat162_rn(make_float2(a0.z, a0.w));
            u.h2[2] = __float22bfloat162_rn(make_float2(a1.x, a1.y));
            u.h2[3] = __float22bfloat162_rn(make_float2(a1.z, a1.w));
            #pragma unroll
            for (int nt = 0; nt < 4; ++nt) {
                const bf16x8 bf = *(const bf16x8*)(wb_base + nt * 16 * (EB + 8) + ks * 32);
                acc[nt] = __builtin_amdgcn_mfma_f32_16x16x32_bf16(u.v, bf, acc[nt], 0, 0, 0);
            }
        }

        // ---- epilogue: relu + bias, dot with W1, reduce over n (16 lanes) ----
        // C layout: n = ln15, m(in-tile) = quad*4 + r
        float part[4];
        #pragma unroll
        for (int r = 0; r < 4; ++r) {
            float s = 0.f;
            #pragma unroll
            for (int nt = 0; nt < 4; ++nt) {
                float hv = acc[nt][r] + biasq[nt];
                hv = hv > 0.f ? hv : 0.f;
                s += hv * w1q[nt];
            }
            part[r] = s;
        }
        #pragma unroll
        for (int m = 1; m < 16; m <<= 1) {
            #pragma unroll
            for (int r = 0; r < 4; ++r)
                part[r] += __shfl_xor(part[r], m, 64);
        }
        if (ln15 == 0) {
            #pragma unroll
            for (int r = 0; r < 4; ++r) {
                const int mg = mt * 16 + quad * 4 + r;
                if (mg < TB) out[(size_t)b * TB + mg] = part[r] + b1v;
            }
        }
    }
}

extern "C" void kernel_launch(void* const* d_in, const int* in_sizes, int n_in,
                              void* d_out, int out_size, void* d_ws, size_t ws_size,
                              hipStream_t stream) {
    const float* query = (const float*)d_in[0];
    const float* keys  = (const float*)d_in[1];
    const float* W0    = (const float*)d_in[2];
    const float* b0    = (const float*)d_in[3];
    const float* W1    = (const float*)d_in[4];
    const float* b1    = (const float*)d_in[5];
    float* out = (float*)d_out;

    lau_kernel<<<1024, 256, 0, stream>>>(query, keys, W0, b0, W1, b1, out);
}